// Round 1
// baseline (210094.409 us; speedup 1.0000x reference)
//
#include <hip/hip_runtime.h>
#include <math.h>

#define D 640
#define NH 4
#define HD 256
#define DFF 2048
#define NL 18
#define VOCAB 262144
#define T 1024
#define EMB_SCALE 25.298221281347036f

// ---------- reductions (all blocks are 256 threads = 4 waves) ----------
__device__ __forceinline__ float wave_reduce_sum(float v) {
#pragma unroll
    for (int off = 32; off > 0; off >>= 1) v += __shfl_down(v, off, 64);
    return v;
}
__device__ __forceinline__ float wave_reduce_max(float v) {
#pragma unroll
    for (int off = 32; off > 0; off >>= 1) v = fmaxf(v, __shfl_down(v, off, 64));
    return v;
}
__device__ float block_sum(float v, float* red) {
    v = wave_reduce_sum(v);
    int lane = threadIdx.x & 63, w = threadIdx.x >> 6;
    __syncthreads();
    if (lane == 0) red[w] = v;
    __syncthreads();
    float s = red[0];
    int nw = blockDim.x >> 6;
    for (int i = 1; i < nw; i++) s += red[i];
    return s;
}
__device__ float block_max(float v, float* red) {
    v = wave_reduce_max(v);
    int lane = threadIdx.x & 63, w = threadIdx.x >> 6;
    __syncthreads();
    if (lane == 0) red[w] = v;
    __syncthreads();
    float s = red[0];
    int nw = blockDim.x >> 6;
    for (int i = 1; i < nw; i++) s = fmaxf(s, red[i]);
    return s;
}

// ---------- embedding gather ----------
__global__ void k_embed(const int* __restrict__ ids, const float* __restrict__ emb,
                        float* __restrict__ x) {
    int i = blockIdx.x * 256 + threadIdx.x;
    if (i >= T * D) return;
    int t = i / D, d = i - t * D;
    x[i] = emb[(long long)ids[t] * D + d] * EMB_SCALE;
}

// ---------- RMSNorm (optionally fused residual add): out = res + rms(in)*(1+w) ----------
__global__ void k_rmsnorm(const float* __restrict__ in, const float* __restrict__ w,
                          const float* __restrict__ res, float* __restrict__ out, int cols) {
    __shared__ float red[8];
    long long row = blockIdx.x;
    const float* r = in + row * cols;
    float ss = 0.f;
    for (int i = threadIdx.x; i < cols; i += blockDim.x) { float v = r[i]; ss += v * v; }
    ss = block_sum(ss, red);
    float scale = rsqrtf(ss / (float)cols + 1e-6f);
    float* o = out + row * cols;
    const float* a = res ? res + row * cols : nullptr;
    for (int i = threadIdx.x; i < cols; i += blockDim.x) {
        float y = r[i] * scale * (1.0f + w[i]);
        o[i] = a ? (a[i] + y) : y;
    }
}

// ---------- per-head RMSNorm over HD + RoPE (in place). one block (256 thr) per row ----------
__global__ void k_qknorm_rope(float* __restrict__ io, const float* __restrict__ w,
                              int pos_div, float base) {
    __shared__ float red[8];
    __shared__ float buf[HD];
    long long row = blockIdx.x;
    float* p = io + row * HD;
    float v = p[threadIdx.x];
    float ss = block_sum(v * v, red);
    float scale = rsqrtf(ss / (float)HD + 1e-6f);
    buf[threadIdx.x] = v * scale * (1.0f + w[threadIdx.x]);
    __syncthreads();
    if (threadIdx.x < HD / 2) {
        float u1 = buf[threadIdx.x], u2 = buf[threadIdx.x + HD / 2];
        float pos = (float)(blockIdx.x / pos_div);
        float fr = powf(base, -((float)threadIdx.x) / (float)(HD / 2));
        float ang = pos * fr;
        float s, c;
        sincosf(ang, &s, &c);
        p[threadIdx.x] = u1 * c - u2 * s;
        p[threadIdx.x + HD / 2] = u1 * s + u2 * c;
    }
}

// ---------- windowed causal attention, one block (256 thr) per (head, t) ----------
__global__ void k_attn(const float* __restrict__ q, const float* __restrict__ k,
                       const float* __restrict__ v, float* __restrict__ ctx, int win) {
    __shared__ float red[8];
    __shared__ float qs[HD];
    __shared__ float sc[T];
    int h = blockIdx.x, t = blockIdx.y;
    int s0 = t - win + 1; if (s0 < 0) s0 = 0;
    int nS = t - s0 + 1;
    qs[threadIdx.x] = q[((long long)t * NH + h) * HD + threadIdx.x];
    __syncthreads();
    const float4* q4 = (const float4*)qs;
    for (int si = threadIdx.x; si < nS; si += blockDim.x) {
        const float4* k4 = (const float4*)(k + (long long)(s0 + si) * HD);
        float acc = 0.f;
#pragma unroll 8
        for (int i = 0; i < HD / 4; i++) {
            float4 a = q4[i], b = k4[i];
            acc += a.x * b.x + a.y * b.y + a.z * b.z + a.w * b.w;
        }
        sc[si] = acc * 0.0625f;
    }
    __syncthreads();
    float m = -1e30f;
    for (int si = threadIdx.x; si < nS; si += blockDim.x) m = fmaxf(m, sc[si]);
    m = block_max(m, red);
    float ssum = 0.f;
    for (int si = threadIdx.x; si < nS; si += blockDim.x) {
        float e = expf(sc[si] - m);
        sc[si] = e;
        ssum += e;
    }
    ssum = block_sum(ssum, red);
    float inv = 1.0f / ssum;
    float acc = 0.f;
    for (int s = 0; s < nS; s++) acc += sc[s] * v[(long long)(s0 + s) * HD + threadIdx.x];
    ctx[((long long)t * NH + h) * HD + threadIdx.x] = acc * inv;
}

// ---------- NT GEMM: C[m][n] = sum_k A[m][k]*B[n][k]; A (M,K), B (N,K) row-major ----------
__global__ void k_gemm_nt(const float* __restrict__ A, const float* __restrict__ B,
                          float* __restrict__ C, int M, int N, int K) {
    int n = blockIdx.x * blockDim.x + threadIdx.x;
    int m = blockIdx.y;
    if (n >= N) return;
    const float4* a4 = (const float4*)(A + (long long)m * K);
    const float4* b4 = (const float4*)(B + (long long)n * K);
    float acc = 0.f;
    int k4 = K >> 2;
#pragma unroll 4
    for (int i = 0; i < k4; i++) {
        float4 a = a4[i], b = b4[i];
        acc += a.x * b.x + a.y * b.y + a.z * b.z + a.w * b.w;
    }
    C[(long long)m * N + n] = acc;
}

// ---------- GELU(tanh) * u, in place into g ----------
__global__ void k_gelu_mul(float* __restrict__ g, const float* __restrict__ u, int n) {
    int i = blockIdx.x * blockDim.x + threadIdx.x;
    if (i >= n) return;
    float x = g[i];
    float th = tanhf(0.7978845608028654f * (x + 0.044715f * x * x * x));
    g[i] = 0.5f * x * (1.0f + th) * u[i];
}

extern "C" void kernel_launch(void* const* d_in, const int* in_sizes, int n_in,
                              void* d_out, int out_size, void* d_ws, size_t ws_size,
                              hipStream_t stream) {
    const int* ids      = (const int*)d_in[0];
    const float* emb    = (const float*)d_in[1];
    const float* ln_in  = (const float*)d_in[2];
    const float* wq     = (const float*)d_in[3];
    const float* wk     = (const float*)d_in[4];
    const float* wv     = (const float*)d_in[5];
    const float* qnw    = (const float*)d_in[6];
    const float* knw    = (const float*)d_in[7];
    const float* wo     = (const float*)d_in[8];
    const float* ln_pa  = (const float*)d_in[9];
    const float* ln_pf  = (const float*)d_in[10];
    const float* wg     = (const float*)d_in[11];
    const float* wu     = (const float*)d_in[12];
    const float* wd     = (const float*)d_in[13];
    const float* ln_ff  = (const float*)d_in[14];
    const float* norm_f = (const float*)d_in[15];
    float* out = (float*)d_out;

    float* ws  = (float*)d_ws;
    float* x   = ws;                 // T*D      running residual
    float* xn  = x   + T * D;        // T*D      normed
    float* q   = xn  + T * D;        // T*NH*HD
    float* kk  = q   + (long long)T * NH * HD;  // T*HD
    float* vv  = kk  + T * HD;       // T*HD
    float* ctx = vv  + T * HD;       // T*NH*HD
    float* tmp = ctx + (long long)T * NH * HD;  // T*D
    float* x3  = tmp + T * D;        // T*D
    float* gg  = x3  + T * D;        // T*DFF
    float* uu  = gg  + (long long)T * DFF;      // T*DFF

    k_embed<<<(T * D + 255) / 256, 256, 0, stream>>>(ids, emb, x);

    for (int l = 0; l < NL; l++) {
        bool is_g = ((l + 1) % 6) == 0;
        float base = is_g ? 1000000.0f : 10000.0f;
        int win = is_g ? 32768 : 512;

        // pre-attn norm
        k_rmsnorm<<<T, 256, 0, stream>>>(x, ln_in + (long long)l * D, nullptr, xn, D);
        // qkv projections
        k_gemm_nt<<<dim3((NH * HD + 255) / 256, T), 256, 0, stream>>>(
            xn, wq + (long long)l * NH * HD * D, q, T, NH * HD, D);
        k_gemm_nt<<<dim3((HD + 255) / 256, T), 256, 0, stream>>>(
            xn, wk + (long long)l * HD * D, kk, T, HD, D);
        k_gemm_nt<<<dim3((HD + 255) / 256, T), 256, 0, stream>>>(
            xn, wv + (long long)l * HD * D, vv, T, HD, D);
        // qk-norm + rope
        k_qknorm_rope<<<T * NH, HD, 0, stream>>>(q, qnw + (long long)l * HD, NH, base);
        k_qknorm_rope<<<T, HD, 0, stream>>>(kk, knw + (long long)l * HD, 1, base);
        // attention
        k_attn<<<dim3(NH, T), HD, 0, stream>>>(q, kk, vv, ctx, win);
        // output proj
        k_gemm_nt<<<dim3((D + 255) / 256, T), 256, 0, stream>>>(
            ctx, wo + (long long)l * D * NH * HD, tmp, T, D, NH * HD);
        // x2 = x + rms(tmp)  (in place into x)
        k_rmsnorm<<<T, 256, 0, stream>>>(tmp, ln_pa + (long long)l * D, x, x, D);
        // x3 = rms(x2)
        k_rmsnorm<<<T, 256, 0, stream>>>(x, ln_pf + (long long)l * D, nullptr, x3, D);
        // ffn
        k_gemm_nt<<<dim3((DFF + 255) / 256, T), 256, 0, stream>>>(
            x3, wg + (long long)l * DFF * D, gg, T, DFF, D);
        k_gemm_nt<<<dim3((DFF + 255) / 256, T), 256, 0, stream>>>(
            x3, wu + (long long)l * DFF * D, uu, T, DFF, D);
        k_gelu_mul<<<(T * DFF + 255) / 256, 256, 0, stream>>>(gg, uu, T * DFF);
        k_gemm_nt<<<dim3((D + 255) / 256, T), 256, 0, stream>>>(
            gg, wd + (long long)l * D * DFF, tmp, T, D, DFF);
        // x = x2 + rms(tmp)  (in place into x)
        k_rmsnorm<<<T, 256, 0, stream>>>(tmp, ln_ff + (long long)l * D, x, x, D);
    }

    // final norm + logits
    k_rmsnorm<<<T, 256, 0, stream>>>(x, norm_f, nullptr, xn, D);
    k_gemm_nt<<<dim3(VOCAB / 256, T), 256, 0, stream>>>(xn, emb, out, T, VOCAB, D);
}